// Round 1
// 854.713 us; speedup vs baseline: 1.0214x; 1.0214x over previous
//
#include <hip/hip_runtime.h>

#define NN 100000
#define NE 1600000
#define NT (NE / 16)          // 100000 wave-tiles, 16 edges each

typedef short v8s __attribute__((ext_vector_type(8)));
typedef float v4f __attribute__((ext_vector_type(4)));
typedef unsigned short v4u16 __attribute__((ext_vector_type(4)));

__device__ __forceinline__ unsigned short f2bf(float f) {
    union { float f; unsigned int u; } v; v.f = f;
    unsigned int r = v.u + 0x7FFFu + ((v.u >> 16) & 1u);  // RNE
    return (unsigned short)(r >> 16);
}

__device__ __forceinline__ v8s pack8(float4 a, float4 b) {
    union { v8s v; unsigned short u[8]; } t;
    t.u[0] = f2bf(a.x); t.u[1] = f2bf(a.y); t.u[2] = f2bf(a.z); t.u[3] = f2bf(a.w);
    t.u[4] = f2bf(b.x); t.u[5] = f2bf(b.y); t.u[6] = f2bf(b.z); t.u[7] = f2bf(b.w);
    return t.v;
}

// Swizzled fragment layout within one 32-k block: element (row, k) at
//   row*32 + ((((k>>3)&3) ^ ((row>>1)&3)) << 3) + (k&7)
// The XOR spreads the 16 rows' 16B chunks across all 8 bank positions of the
// 128B window -> ds_read_b128 fragment reads are 2-way (free) instead of 8-way.
__device__ __forceinline__ int wfrag(int row, int k) {   // k in 0..31
    return row * 32 + ((((k >> 3) & 3) ^ ((row >> 1) & 3)) << 3) + (k & 7);
}
__device__ __forceinline__ int hoff(int m, int k) {      // k in 0..63, 16-row blocks
    return (k >> 5) * 512 + m * 32 + ((((k >> 3) & 3) ^ ((m >> 1) & 3)) << 3) + (k & 7);
}

// Node kernel keeps the old (unswizzled) layout helper.
__device__ __forceinline__ void store_bf4(unsigned short* base, int row, int k, float4 v) {
    v4u16 p;
    p.x = f2bf(v.x); p.y = f2bf(v.y); p.z = f2bf(v.z); p.w = f2bf(v.w);
    *(v4u16*)(base + ((k >> 5) * 2048 + row * 32 + (k & 31))) = p;
}

#define MFMA16(acc, a, b) acc = __builtin_amdgcn_mfma_f32_16x16x32_bf16(a, b, acc, 0, 0, 0)

// ---------------------------------------------------------------------------
// Edge kernel, barrier-free per-wave version.
// Each wave owns a 16-edge tile end-to-end:
//   A-fragments gathered global->register (no A LDS, no staging barrier),
//   3-layer MLP with weights in swizzled LDS (conflict-free b-frag reads),
//   inter-layer transpose via 2KiB per-wave scratch (wave-local, no barrier),
//   f32 atomic scatter that is never drained by a barrier.
// LDS: weights 40KiB + 8 waves * 2KiB scratch = 56KiB -> 2 blocks/CU,
// 512 threads/block -> 16 waves/CU (__launch_bounds__(512,4) caps VGPR<=128).
// ---------------------------------------------------------------------------
__global__ __launch_bounds__(512, 4) void edge_kernel(
    const float* __restrict__ x, const float* __restrict__ e,
    const int* __restrict__ snd, const int* __restrict__ rcv,
    const float* __restrict__ We1, const float* __restrict__ be1,
    const float* __restrict__ We2, const float* __restrict__ be2,
    const float* __restrict__ We3, const float* __restrict__ be3,
    float* agg)
{
    extern __shared__ unsigned short smem[];
    unsigned short* WT1 = smem;             // 12288 u16 (6 kb blocks of 64x32)
    unsigned short* WT2 = WT1 + 12288;      // 4096
    unsigned short* WT3 = WT2 + 4096;       // 4096
    unsigned short* HS  = WT3 + 4096;       // 8 * 1024 per-wave scratch

    const int tid = threadIdx.x;

    // Stage weights once, swizzled fragment layout.
    for (int idx = tid; idx < 192 * 64; idx += 512) {
        int k = idx >> 6, n = idx & 63;
        WT1[(k >> 5) * 2048 + wfrag(n, k & 31)] = f2bf(We1[idx]);
    }
    for (int idx = tid; idx < 64 * 64; idx += 512) {
        int k = idx >> 6, n = idx & 63;
        int off = (k >> 5) * 2048 + wfrag(n, k & 31);
        WT2[off] = f2bf(We2[idx]);
        WT3[off] = f2bf(We3[idx]);
    }

    const int lane = tid & 63;
    const int wv   = tid >> 6;
    const int l15  = lane & 15;
    const int quad = lane >> 4;
    unsigned short* H = HS + wv * 1024;     // 16 rows x 64 k, swizzled

    float b1v[4], b2v[4], b3v[4];
#pragma unroll
    for (int nt = 0; nt < 4; ++nt) {
        b1v[nt] = be1[nt * 16 + l15];
        b2v[nt] = be2[nt * 16 + l15];
        b3v[nt] = be3[nt * 16 + l15];
    }

    // Per-lane fragment offset (u16) within any kb block, swizzled; 2-way free.
    const int swz = l15 * 32 + ((quad ^ ((l15 >> 1) & 3)) << 3);

    __syncthreads();   // weights ready; the ONLY block barrier.

    const int nwaves = gridDim.x * (blockDim.x >> 6);   // 512*8 = 4096
    int wt = blockIdx.x * (blockDim.x >> 6) + wv;

    // Prefetched indices for the current tile.
    int er = wt * 16 + l15;
    int s0 = snd[er], r0 = rcv[er];

    while (wt < NT) {
        const int ebase = wt * 16;
        const int s = s0, rcur = r0;

        // ---- Gather A directly into registers (lane owns row=l15, k=kb*32+quad*8) ----
        const float* erow = e + (size_t)(ebase + l15) * 64 + quad * 8;
        const float* xs   = x + (size_t)s    * 64 + quad * 8;
        const float* xr   = x + (size_t)rcur * 64 + quad * 8;

        float4 e00 = *(const float4*)(erow);
        float4 e01 = *(const float4*)(erow + 4);
        float4 e10 = *(const float4*)(erow + 32);
        float4 e11 = *(const float4*)(erow + 36);
        float4 s00 = *(const float4*)(xs);
        float4 s01 = *(const float4*)(xs + 4);
        float4 s10 = *(const float4*)(xs + 32);
        float4 s11 = *(const float4*)(xs + 36);
        float4 r00 = *(const float4*)(xr);
        float4 r01 = *(const float4*)(xr + 4);
        float4 r10 = *(const float4*)(xr + 32);
        float4 r11 = *(const float4*)(xr + 36);

        // Prefetch next tile's indices (breaks the idx->row dependent chain).
        const int wtn = wt + nwaves;
        if (wtn < NT) {
            int ern = wtn * 16 + l15;
            s0 = snd[ern];
            r0 = rcv[ern];
        }

        v8s af[6];
        af[0] = pack8(e00, e01); af[1] = pack8(e10, e11);
        af[2] = pack8(s00, s01); af[3] = pack8(s10, s11);
        af[4] = pack8(r00, r01); af[5] = pack8(r10, r11);

        // ---- Layer 1: [16,192] @ [192,64], relu -> H ----
        {
            v4f acc[4];
#pragma unroll
            for (int nt = 0; nt < 4; ++nt) acc[nt] = (v4f){0.f, 0.f, 0.f, 0.f};
#pragma unroll
            for (int kb = 0; kb < 6; ++kb) {
#pragma unroll
                for (int nt = 0; nt < 4; ++nt) {
                    v8s bf = *(const v8s*)(WT1 + kb * 2048 + nt * 512 + swz);
                    MFMA16(acc[nt], af[kb], bf);
                }
            }
#pragma unroll
            for (int nt = 0; nt < 4; ++nt) {
                int kk = nt * 16 + l15;
#pragma unroll
                for (int r = 0; r < 4; ++r) {
                    float v = acc[nt][r] + b1v[nt];
                    v = v > 0.f ? v : 0.f;
                    H[hoff(quad * 4 + r, kk)] = f2bf(v);
                }
            }
        }

        // ---- Layer 2: [16,64] @ [64,64], relu -> H (in-place; wave-local order-safe) ----
        {
            v8s a0 = *(const v8s*)(H + swz);
            v8s a1 = *(const v8s*)(H + 512 + swz);
            v4f acc[4];
#pragma unroll
            for (int nt = 0; nt < 4; ++nt) acc[nt] = (v4f){0.f, 0.f, 0.f, 0.f};
#pragma unroll
            for (int nt = 0; nt < 4; ++nt) {
                v8s bf0 = *(const v8s*)(WT2 + nt * 512 + swz);
                MFMA16(acc[nt], a0, bf0);
                v8s bf1 = *(const v8s*)(WT2 + 2048 + nt * 512 + swz);
                MFMA16(acc[nt], a1, bf1);
            }
#pragma unroll
            for (int nt = 0; nt < 4; ++nt) {
                int kk = nt * 16 + l15;
#pragma unroll
                for (int r = 0; r < 4; ++r) {
                    float v = acc[nt][r] + b2v[nt];
                    v = v > 0.f ? v : 0.f;
                    H[hoff(quad * 4 + r, kk)] = f2bf(v);
                }
            }
        }

        // ---- Layer 3: [16,64] @ [64,64] (no relu) -> atomic scatter ----
        {
            v8s a0 = *(const v8s*)(H + swz);
            v8s a1 = *(const v8s*)(H + 512 + swz);
            v4f acc[4];
#pragma unroll
            for (int nt = 0; nt < 4; ++nt) acc[nt] = (v4f){0.f, 0.f, 0.f, 0.f};
#pragma unroll
            for (int nt = 0; nt < 4; ++nt) {
                v8s bf0 = *(const v8s*)(WT3 + nt * 512 + swz);
                MFMA16(acc[nt], a0, bf0);
                v8s bf1 = *(const v8s*)(WT3 + 2048 + nt * 512 + swz);
                MFMA16(acc[nt], a1, bf1);
            }
#pragma unroll
            for (int ri = 0; ri < 4; ++ri) {
                int dst = __shfl(rcur, quad * 4 + ri, 16);   // rcv[ebase + quad*4 + ri]
                float* aggrow = agg + (size_t)dst * 64;
#pragma unroll
                for (int nt = 0; nt < 4; ++nt) {
                    unsafeAtomicAdd(aggrow + nt * 16 + l15, acc[nt][ri] + b3v[nt]);
                }
            }
        }

        wt = wtn;
    }
}

// ---------------------------------------------------------------------------
// Node kernel: unchanged from the verified version.
// ---------------------------------------------------------------------------
__global__ __launch_bounds__(256, 2) void node_kernel(
    const float* __restrict__ x,
    const float* __restrict__ Wn1, const float* __restrict__ bn1,
    const float* __restrict__ Wn2, const float* __restrict__ bn2,
    const float* __restrict__ Wn3, const float* __restrict__ bn3,
    float* aggout)
{
    extern __shared__ unsigned short smem[];
    unsigned short* WT1 = smem;             // 8192 (kb 0..3)
    unsigned short* WT2 = WT1 + 8192;       // 4096
    unsigned short* WT3 = WT2 + 4096;       // 4096
    unsigned short* A   = WT3 + 4096;       // 8192 (kb 0..3); H1 kb0-1, H2 kb2-3

    const int tid = threadIdx.x;

    for (int idx = tid; idx < 128 * 64; idx += 256) {
        int k = idx >> 6, n = idx & 63;
        WT1[(k >> 5) * 2048 + n * 32 + (k & 31)] = f2bf(Wn1[idx]);
    }
    for (int idx = tid; idx < 64 * 64; idx += 256) {
        int k = idx >> 6, n = idx & 63;
        int off = (k >> 5) * 2048 + n * 32 + (k & 31);
        WT2[off] = f2bf(Wn2[idx]);
        WT3[off] = f2bf(Wn3[idx]);
    }

    const int lane = tid & 63;
    const int wv   = tid >> 6;
    const int l15  = lane & 15;
    const int quad = lane >> 4;
    const int astrip = wv * 16;

    float b1v[4], b2v[4], b3v[4];
#pragma unroll
    for (int nt = 0; nt < 4; ++nt) {
        b1v[nt] = bn1[nt * 16 + l15];
        b2v[nt] = bn2[nt * 16 + l15];
        b3v[nt] = bn3[nt * 16 + l15];
    }

    const int arow = (astrip + l15) * 32 + quad * 8;
    const int brow = l15 * 32 + quad * 8;
    const int nbase = blockIdx.x * 64;

    __syncthreads();

#pragma unroll
    for (int t = 0; t < 4; ++t) {
        int idx = tid + t * 256;
        int row = idx >> 4;
        int k0  = (idx & 15) * 4;
        int node = nbase + row;
        float4 vx = {0.f, 0.f, 0.f, 0.f}, va = {0.f, 0.f, 0.f, 0.f};
        if (node < NN) {
            vx = *(const float4*)(x + (size_t)node * 64 + k0);
            va = *(const float4*)(aggout + (size_t)node * 64 + k0);
        }
        store_bf4(A, row, k0, vx);
        store_bf4(A, row, 64 + k0, va);
    }
    __syncthreads();

    {
        v4f acc[4];
#pragma unroll
        for (int nt = 0; nt < 4; ++nt) acc[nt] = (v4f){0.f, 0.f, 0.f, 0.f};
#pragma unroll
        for (int kb = 0; kb < 4; ++kb) {
            v8s af = *(const v8s*)(A + kb * 2048 + arow);
#pragma unroll
            for (int nt = 0; nt < 4; ++nt) {
                v8s bf = *(const v8s*)(WT1 + kb * 2048 + brow + nt * 512);
                MFMA16(acc[nt], af, bf);
            }
        }
#pragma unroll
        for (int nt = 0; nt < 4; ++nt) {
            int kk = nt * 16 + l15;
#pragma unroll
            for (int r = 0; r < 4; ++r) {
                int m = astrip + quad * 4 + r;
                float v = acc[nt][r] + b1v[nt];
                v = v > 0.f ? v : 0.f;
                A[(kk >> 5) * 2048 + m * 32 + (kk & 31)] = f2bf(v);
            }
        }
    }

    {
        v4f acc[4];
#pragma unroll
        for (int nt = 0; nt < 4; ++nt) acc[nt] = (v4f){0.f, 0.f, 0.f, 0.f};
#pragma unroll
        for (int kb = 0; kb < 2; ++kb) {
            v8s af = *(const v8s*)(A + kb * 2048 + arow);
#pragma unroll
            for (int nt = 0; nt < 4; ++nt) {
                v8s bf = *(const v8s*)(WT2 + kb * 2048 + brow + nt * 512);
                MFMA16(acc[nt], af, bf);
            }
        }
#pragma unroll
        for (int nt = 0; nt < 4; ++nt) {
            int kk = nt * 16 + l15;
#pragma unroll
            for (int r = 0; r < 4; ++r) {
                int m = astrip + quad * 4 + r;
                float v = acc[nt][r] + b2v[nt];
                v = v > 0.f ? v : 0.f;
                A[(2 + (kk >> 5)) * 2048 + m * 32 + (kk & 31)] = f2bf(v);
            }
        }
    }

    {
        v4f acc[4];
#pragma unroll
        for (int nt = 0; nt < 4; ++nt) acc[nt] = (v4f){0.f, 0.f, 0.f, 0.f};
#pragma unroll
        for (int kb = 0; kb < 2; ++kb) {
            v8s af = *(const v8s*)(A + (2 + kb) * 2048 + arow);
#pragma unroll
            for (int nt = 0; nt < 4; ++nt) {
                v8s bf = *(const v8s*)(WT3 + kb * 2048 + brow + nt * 512);
                MFMA16(acc[nt], af, bf);
            }
        }
#pragma unroll
        for (int r = 0; r < 4; ++r) {
            int node = nbase + astrip + quad * 4 + r;
            if (node < NN) {
#pragma unroll
                for (int nt = 0; nt < 4; ++nt) {
                    aggout[(size_t)node * 64 + nt * 16 + l15] = acc[nt][r] + b3v[nt];
                }
            }
        }
    }
}

extern "C" void kernel_launch(void* const* d_in, const int* in_sizes, int n_in,
                              void* d_out, int out_size, void* d_ws, size_t ws_size,
                              hipStream_t stream) {
    const float* x   = (const float*)d_in[0];
    const float* e   = (const float*)d_in[1];
    const int*   snd = (const int*)d_in[2];
    const int*   rcv = (const int*)d_in[3];
    const float* We1 = (const float*)d_in[4];  const float* be1 = (const float*)d_in[5];
    const float* We2 = (const float*)d_in[6];  const float* be2 = (const float*)d_in[7];
    const float* We3 = (const float*)d_in[8];  const float* be3 = (const float*)d_in[9];
    const float* Wn1 = (const float*)d_in[10]; const float* bn1 = (const float*)d_in[11];
    const float* Wn2 = (const float*)d_in[12]; const float* bn2 = (const float*)d_in[13];
    const float* Wn3 = (const float*)d_in[14]; const float* bn3 = (const float*)d_in[15];
    float* out = (float*)d_out;

    // out doubles as the agg buffer (exactly N*64 floats); zero it first.
    hipMemsetAsync(out, 0, (size_t)NN * 64 * sizeof(float), stream);

    // 512 blocks x 512 threads = 4096 waves, 56KiB LDS -> 2 blocks/CU, 16 waves/CU.
    edge_kernel<<<512, 512, 57344, stream>>>(x, e, snd, rcv,
                                             We1, be1, We2, be2, We3, be3,
                                             out);

    node_kernel<<<(NN + 63) / 64, 256, 49152, stream>>>(x,
                                                        Wn1, bn1, Wn2, bn2, Wn3, bn3,
                                                        out);
}